// Round 11
// baseline (35.423 us; speedup 1.0000x reference)
//
#include <hip/hip_runtime.h>

#define CDIM 128
#define HDIM 128
#define LIM  40960   // nodes cached in edge LDS (x4 B = 163840 B = full 160 KiB)

typedef short bf16x8 __attribute__((ext_vector_type(8)));
typedef float f32x16 __attribute__((ext_vector_type(16)));

// Dynamic cast-queue counter. Zero at module load (first call); K2 re-arms it
// to zero (device-scope atomicExch) for the next call — K2 is stream-ordered
// after K1 has fully drained the queue, so every kernel_launch sees 0.
__device__ int g_cast_counter = 0;

// fp32 -> bf16 bits, round-to-nearest-even
static __device__ __forceinline__ short f2bf(float f) {
    union { float f; unsigned u; } v; v.f = f;
    unsigned r = v.u + 0x7FFFu + ((v.u >> 16) & 1u);
    return (short)(r >> 16);
}
static __device__ __forceinline__ unsigned pack2(float a, float b) {
    return (unsigned)(unsigned short)f2bf(a) | ((unsigned)(unsigned short)f2bf(b) << 16);
}

// ---------------------------------------------------------------------------
// K1: node MLP -> score table  +  dynamically-scheduled cast stream.
// Node part identical to R8 (256 thr / 4 waves / 128 nodes / 2 blocks/CU).
// After its node tile, each BLOCK (one atomic per block, broadcast via LDS)
// drains 32 KB cast chunks: out[2E + i] = float(ein[i]). Output is
// placement-invariant -> deterministic regardless of chunk assignment.
// ---------------------------------------------------------------------------
__global__ __launch_bounds__(256, 2) void node_mfma(
    const float* __restrict__ x,
    const float* __restrict__ W1, const float* __restrict__ b1,
    const float* __restrict__ W2, const float* __restrict__ b2,
    const float* __restrict__ We,
    const int* __restrict__ ein,
    unsigned* __restrict__ tab, float* __restrict__ out, int N, int E)
{
    __shared__ __align__(16) short wfA[2][16384];  // 64 KB: both layers
    __shared__ __align__(16) float cv[512];        // b1 | b2 | Wq | Wk
    __shared__ int s_chunk;

    const int tid = threadIdx.x;
    const int l   = tid & 63;
    const int col = l & 31;
    const int hi  = l >> 5;
    const int node = blockIdx.x * 128 + (tid >> 6) * 32 + col;

    // ---- issue ALL x loads first (latency hides under W transform) ----
    const int nclamp = (node < N) ? node : (N - 1);
    const float* xb = &x[(size_t)nclamp * CDIM + hi * 8];
    float4 xr[16];
#pragma unroll
    for (int ks = 0; ks < 8; ks++) {
        xr[2 * ks]     = *(const float4*)(xb + ks * 16);
        xr[2 * ks + 1] = *(const float4*)(xb + ks * 16 + 4);
    }

    // ---- W transform: both layers, dest-linear, 1 ds_write_b128/iter ----
#pragma unroll
    for (int t = 0; t < 16; t++) {
        int tt = t * 256 + tid;
        int layer = tt >> 11;
        int rem = tt & 2047;
        int lv = rem & 63, ks = (rem >> 6) & 7, ct = rem >> 9;
        const float* Wsrc = layer ? W2 : W1;
        int k0 = ks * 16 + 8 * (lv >> 5);
        int n  = ct * 32 + (lv & 31);
        bf16x8 wv;
#pragma unroll
        for (int j = 0; j < 8; j++) wv[j] = f2bf(Wsrc[(k0 + j) * HDIM + n]);
        *(bf16x8*)&wfA[layer][rem * 8] = wv;
    }
    for (int i = tid; i < 512; i += 256)
        cv[i] = (i < 128) ? b1[i] : (i < 256) ? b2[i - 128] : We[i - 256];

    // ---- convert x to bf16 fragments ----
    bf16x8 af[8];
#pragma unroll
    for (int ks = 0; ks < 8; ks++) {
        float4 v0 = xr[2 * ks], v1 = xr[2 * ks + 1];
        af[ks][0] = f2bf(v0.x); af[ks][1] = f2bf(v0.y);
        af[ks][2] = f2bf(v0.z); af[ks][3] = f2bf(v0.w);
        af[ks][4] = f2bf(v1.x); af[ks][5] = f2bf(v1.y);
        af[ks][6] = f2bf(v1.z); af[ks][7] = f2bf(v1.w);
    }
    __syncthreads();   // wfA + cv ready

    const f32x16 zz = {0.f,0.f,0.f,0.f,0.f,0.f,0.f,0.f,0.f,0.f,0.f,0.f,0.f,0.f,0.f,0.f};

    // ---- layer 1: A = W1-frag (LDS, lane-linear), B = x^T-frag (regs) ----
    f32x16 acc[4];
#pragma unroll
    for (int ct = 0; ct < 4; ct++) acc[ct] = zz;
#pragma unroll
    for (int ks = 0; ks < 8; ks++) {
#pragma unroll
        for (int ct = 0; ct < 4; ct++) {
            bf16x8 wfrag = *(const bf16x8*)&wfA[0][((ct * 8 + ks) * 64 + l) * 8];
            acc[ct] = __builtin_amdgcn_mfma_f32_32x32x16_bf16(wfrag, af[ks], acc[ct], 0, 0, 0);
        }
    }

    // ---- h1 = relu(D1 + b1): pack own 64 features as bf16 pairs ----
    unsigned P[4][4][2], Q[4][4][2];
#pragma unroll
    for (int ct = 0; ct < 4; ct++) {
#pragma unroll
        for (int g = 0; g < 4; g++) {
            float4 bv = *(const float4*)&cv[32 * ct + 8 * g + 4 * hi];
            float h0  = fmaxf(acc[ct][4 * g + 0] + bv.x, 0.f);
            float h1v = fmaxf(acc[ct][4 * g + 1] + bv.y, 0.f);
            float h2v = fmaxf(acc[ct][4 * g + 2] + bv.z, 0.f);
            float h3v = fmaxf(acc[ct][4 * g + 3] + bv.w, 0.f);
            P[ct][g][0] = pack2(h0, h1v);
            P[ct][g][1] = pack2(h2v, h3v);
        }
    }
#pragma unroll
    for (int ct = 0; ct < 4; ct++)
#pragma unroll
        for (int g = 0; g < 4; g++)
#pragma unroll
            for (int p = 0; p < 2; p++)
                Q[ct][g][p] = (unsigned)__shfl_xor((int)P[ct][g][p], 32, 64);

    // ---- layer 2: B2 frag in-register; A = W2-frag from LDS ----
    f32x16 acc2[4];
#pragma unroll
    for (int ct = 0; ct < 4; ct++) acc2[ct] = zz;
#pragma unroll
    for (int ks2 = 0; ks2 < 8; ks2++) {
        const int c  = ks2 >> 1;
        const int s2 = (ks2 & 1) * 2;
        union { bf16x8 v; unsigned u[4]; } bb;
        bb.u[0] = hi ? Q[c][s2 + 1][0] : P[c][s2][0];
        bb.u[1] = hi ? Q[c][s2 + 1][1] : P[c][s2][1];
        bb.u[2] = hi ? P[c][s2 + 1][0] : Q[c][s2][0];
        bb.u[3] = hi ? P[c][s2 + 1][1] : Q[c][s2][1];
#pragma unroll
        for (int ct = 0; ct < 4; ct++) {
            bf16x8 wfrag = *(const bf16x8*)&wfA[1][((ct * 8 + ks2) * 64 + l) * 8];
            acc2[ct] = __builtin_amdgcn_mfma_f32_32x32x16_bf16(wfrag, bb.v, acc2[ct], 0, 0, 0);
        }
    }

    // ---- epilogue: partial dot over own 64 n2, combine across lane pair ----
    float pq = 0.f, pk = 0.f;
#pragma unroll
    for (int ct = 0; ct < 4; ct++) {
#pragma unroll
        for (int g = 0; g < 4; g++) {
            float4 b2v = *(const float4*)&cv[128 + 32 * ct + 8 * g + 4 * hi];
            float4 wqv = *(const float4*)&cv[256 + 32 * ct + 8 * g + 4 * hi];
            float4 wkv = *(const float4*)&cv[384 + 32 * ct + 8 * g + 4 * hi];
            const float* b2a = (const float*)&b2v;
            const float* wqa = (const float*)&wqv;
            const float* wka = (const float*)&wkv;
#pragma unroll
            for (int i = 0; i < 4; i++) {
                float hv = fmaxf(acc2[ct][4 * g + i] + b2a[i], 0.f);
                pq = fmaf(hv, wqa[i], pq);
                pk = fmaf(hv, wka[i], pk);
            }
        }
    }
    pq += __shfl_xor(pq, 32, 64);
    pk += __shfl_xor(pk, 32, 64);
    if (hi == 0 && node < N) tab[node] = pack2(pq, pk);

    // ---- cast stream via atomic chunk queue: ONE atomic per BLOCK ----
    {
        const int C4  = (E * 2) >> 2;              // total int4 units (2E/4)
        const int NCH = (C4 + 2047) >> 11;         // chunks of 2048 int4
        const int4* ein4 = (const int4*)ein;
        float4* o4 = (float4*)out + (E >> 1);      // casts start at float 2E
        for (;;) {
            __syncthreads();                       // protect s_chunk readers
            if (tid == 0) s_chunk = atomicAdd(&g_cast_counter, 1);
            __syncthreads();
            int c = s_chunk;                       // block-uniform
            if (c >= NCH) break;
            int base = c << 11;
#pragma unroll
            for (int i = 0; i < 8; i++) {
                int idx = base + i * 256 + tid;
                if (idx < C4) {
                    int4 v = ein4[idx];
                    o4[idx] = make_float4((float)v.x, (float)v.y, (float)v.z, (float)v.w);
                }
            }
        }
    }
}

// ---------------------------------------------------------------------------
// K2: pure edge scores. 512 thr x 256 blocks. Re-arms the cast-queue counter
// (device-scope atomic) for the next kernel_launch.
// Issue table DMA -> preload iter-0 indices -> barrier -> pipelined
// gather+store loop (load iter i+1 while scoring iter i).
// ---------------------------------------------------------------------------
__global__ __launch_bounds__(512) void edge_kernel(
    const int* __restrict__ eip, const int* __restrict__ ein,
    const unsigned* __restrict__ tab, const float* __restrict__ be_p,
    float* __restrict__ out, int E)
{
    __shared__ __align__(16) unsigned lt[LIM];   // 163840 B
    const int tid = threadIdx.x;
    const int wv = tid >> 6, ln = tid & 63;      // 8 waves

    if (blockIdx.x == 0 && tid == 0) atomicExch(&g_cast_counter, 0);  // re-arm

    // ---- issue async staging DMA: 10240 uint4 = 8 waves x 20 iters ----
    const uint4* tg4 = (const uint4*)tab;
#pragma unroll
    for (int t = 0; t < LIM / 4 / 512; t++) {
        int c = (t * 8 + wv) * 64;
        __builtin_amdgcn_global_load_lds(
            (const __attribute__((address_space(1))) void*)(tg4 + c + ln),
            (__attribute__((address_space(3))) void*)((char*)lt + (size_t)c * 16),
            16, 0, 0);
    }
    __builtin_amdgcn_sched_barrier(0);

    const int U = E >> 2;                         // 4-edge units
    const int chunk = (U + gridDim.x - 1) / gridDim.x;
    const int ustart = blockIdx.x * chunk;
    const int uend = min(U, ustart + chunk);

    const int4* eip4 = (const int4*)eip;
    const int4* ein4 = (const int4*)ein;
    float4* out4 = (float4*)out;

    // ---- preload iteration 0 (overlaps DMA) ----
    int u = ustart + tid;
    bool v = u < uend;
    int4 ps = {0,0,0,0}, pd = {0,0,0,0}, ns = {0,0,0,0}, nd = {0,0,0,0};
    if (v) { ps = eip4[u]; pd = eip4[U + u]; ns = ein4[u]; nd = ein4[U + u]; }

    __syncthreads();   // drains DMA (vmcnt) + makes lt visible

    const float be = be_p[0];
#define GATHER(i) ((i) < LIM ? lt[i] : tab[i])
#define SCORE(us, ud) (__uint_as_float((us) << 16) + __uint_as_float((ud) & 0xFFFF0000u) + be)
    while (v) {
        int un = u + 512;
        bool vn = un < uend;
        int4 ps2 = {0,0,0,0}, pd2 = {0,0,0,0}, ns2 = {0,0,0,0}, nd2 = {0,0,0,0};
        if (vn) { ps2 = eip4[un]; pd2 = eip4[U + un]; ns2 = ein4[un]; nd2 = ein4[U + un]; }

        unsigned a0 = GATHER(ps.x), a1 = GATHER(ps.y), a2 = GATHER(ps.z), a3 = GATHER(ps.w);
        unsigned b0 = GATHER(pd.x), b1 = GATHER(pd.y), b2 = GATHER(pd.z), b3 = GATHER(pd.w);
        unsigned c0 = GATHER(ns.x), c1 = GATHER(ns.y), c2 = GATHER(ns.z), c3 = GATHER(ns.w);
        unsigned d0 = GATHER(nd.x), d1 = GATHER(nd.y), d2 = GATHER(nd.z), d3 = GATHER(nd.w);
        out4[u]     = make_float4(SCORE(a0,b0), SCORE(a1,b1), SCORE(a2,b2), SCORE(a3,b3));
        out4[U + u] = make_float4(SCORE(c0,d0), SCORE(c1,d1), SCORE(c2,d2), SCORE(c3,d3));

        u = un; v = vn; ps = ps2; pd = pd2; ns = ns2; nd = nd2;
    }
#undef GATHER
#undef SCORE
}

extern "C" void kernel_launch(void* const* d_in, const int* in_sizes, int n_in,
                              void* d_out, int out_size, void* d_ws, size_t ws_size,
                              hipStream_t stream) {
    const float* x   = (const float*)d_in[0];
    const int*   eip = (const int*)d_in[1];
    const int*   ein = (const int*)d_in[2];
    // d_in[3] = batch (unused)
    const float* W1  = (const float*)d_in[4];
    const float* b1  = (const float*)d_in[5];
    const float* W2  = (const float*)d_in[6];
    const float* b2  = (const float*)d_in[7];
    const float* We  = (const float*)d_in[8];
    const float* be  = (const float*)d_in[9];

    const int N = in_sizes[0] / CDIM;
    const int E = in_sizes[1] / 2;

    unsigned* tab = (unsigned*)d_ws;   // N*4 B packed bf16x2 score table

    node_mfma<<<(N + 127) / 128, 256, 0, stream>>>(x, W1, b1, W2, b2, We, ein,
                                                   tab, (float*)d_out, N, E);
    edge_kernel<<<256, 512, 0, stream>>>(eip, ein, tab, be, (float*)d_out, E);
}